// Round 3
// baseline (615.926 us; speedup 1.0000x reference)
//
#include <hip/hip_runtime.h>
#include <hip/hip_cooperative_groups.h>

namespace cg = cooperative_groups;

typedef float __attribute__((ext_vector_type(4))) f32x4;

#define BB 256
#define NN 196
#define DD 768
#define PP 32
#define TOPK 5
#define NROW 216           /* 20 + 196 */

/* fp32 element offsets in d_out (flat concat in return order) */
#define OUT0_ELTS (BB * NROW * DD)   /* 42467328 */
#define RS_OFF    OUT0_ELTS
#define SIM_OFF   (OUT0_ELTS + 1)
#define IDX_OFF   (OUT0_ELTS + 1 + BB * PP)

/* ws layout (byte offsets) */
#define WS_PNORM  0                          /* 32*768  fp32 =  98304 B */
#define WS_PEMB   98304                      /* 128*768 fp32 = 393216 B */
#define WS_PART   491520                     /* 256 fp32     =   1024 B */

/* ---- Single cooperative kernel, 256 blocks x 768 threads (1 block/CU).
   Roles:
     blocks 0..31  : patch-embed prompt b (4 positions x 768 channels),
                     conv dot-products INTERLEAVED into the NT copy loop
                     (copy is HBM-bound, conv is VALU/L2-bound -> overlap).
     blocks 32..63 : prompt_key L2-norm row (b-32), done before copy.
     all blocks    : copy 196 x-rows -> out0[20..216) (NT), column mean,
                     L2-norm, 32 sim dots, wave-parallel top-5, gather.
   grid.sync #1: pemb/pnorm produced -> consumed (sims + gather).
   grid.sync #2: per-block top-5 partials -> block 0 reduces reduce_sim. */
__global__ __launch_bounds__(768, 3) void k_all(
    const float* __restrict__ x, const float* __restrict__ prompt,
    const float* __restrict__ pkey, const float* __restrict__ cw,
    const float* __restrict__ cb, float* __restrict__ out,
    float* __restrict__ pnorm, float* __restrict__ pemb,
    float* __restrict__ wspart)
{
    const int b = blockIdx.x;
    const int t = threadIdx.x;

    __shared__ float patch[4 * DD];     /* 12 KB, prep blocks only */
    __shared__ f32x4 comb[768];         /* 12 KB */
    __shared__ float xm[768];
    __shared__ float sims[PP];
    __shared__ float wred[12];
    __shared__ float rsh;
    __shared__ int lidx[TOPK];

    const bool is_pemb = (b < PP);

    /* ---- prompt_key L2 normalize (blocks 32..63), cheap, pre-copy ---- */
    if (b >= PP && b < 2 * PP) {
        const int p = b - PP;
        const float v = pkey[(size_t)p * DD + t];
        float sq = v * v;
#pragma unroll
        for (int off = 32; off; off >>= 1) sq += __shfl_down(sq, off);
        if ((t & 63) == 0) wred[t >> 6] = sq;
        __syncthreads();
        if (t == 0) {
            float tot = 0.f;
            for (int i = 0; i < 12; ++i) tot += wred[i];
            rsh = rsqrtf(fmaxf(tot, 1e-12f));
        }
        __syncthreads();
        pnorm[(size_t)p * DD + t] = v * rsh;
    }

    /* ---- stage 4 patches of prompt b into LDS (prep blocks) ---- */
    if (is_pemb) {
        for (int idx = t; idx < 4 * DD; idx += 768) {
            const int j = idx / DD, kk = idx - j * DD;
            const int ch = kk >> 8, rem = kk & 255;
            const int kh = rem >> 4, kw = rem & 15;
            patch[idx] = prompt[(size_t)b * 3072 + (size_t)ch * 1024
                                + ((j >> 1) * 16 + kh) * 32 + (j & 1) * 16 + kw];
        }
    }
    __syncthreads();

    /* ---- copy + column-sum, with conv FMAs interleaved (prep blocks) ---- */
    const int g = t / 192, c = t - g * 192;       /* c: float4-column 0..191 */
    const float* xb = x + (size_t)b * (NN * DD);
    float* ob = out + (size_t)b * (NROW * DD) + 20 * DD;
    const float4* wrow = (const float4*)(cw + (size_t)t * DD);
    const float4* q0p = (const float4*)(patch);
    const float4* q1p = (const float4*)(patch + DD);
    const float4* q2p = (const float4*)(patch + 2 * DD);
    const float4* q3p = (const float4*)(patch + 3 * DD);
    float a0 = 0.f, a1 = 0.f, a2 = 0.f, a3 = 0.f;
    f32x4 s = (f32x4)(0.f);
#pragma unroll
    for (int o = 0; o < 7; ++o) {
        f32x4 vv[7];
#pragma unroll
        for (int i = 0; i < 7; ++i) {
            const int row = g + 4 * (o * 7 + i);
            vv[i] = __builtin_nontemporal_load((const f32x4*)(xb + (size_t)row * DD) + c);
        }
        if (is_pemb) {
            const int k0 = o * 28;
            const int k1 = (o == 6) ? 192 : (k0 + 28);
#pragma unroll 4
            for (int kk = k0; kk < k1; ++kk) {
                const float4 w = wrow[kk];
                const float4 q0 = q0p[kk], q1 = q1p[kk], q2 = q2p[kk], q3 = q3p[kk];
                a0 += q0.x * w.x + q0.y * w.y + q0.z * w.z + q0.w * w.w;
                a1 += q1.x * w.x + q1.y * w.y + q1.z * w.z + q1.w * w.w;
                a2 += q2.x * w.x + q2.y * w.y + q2.z * w.z + q2.w * w.w;
                a3 += q3.x * w.x + q3.y * w.y + q3.z * w.z + q3.w * w.w;
            }
        }
#pragma unroll
        for (int i = 0; i < 7; ++i) {
            const int row = g + 4 * (o * 7 + i);
            s += vv[i];
            __builtin_nontemporal_store(vv[i], (f32x4*)(ob + (size_t)row * DD) + c);
        }
    }
    if (is_pemb) {
        const float bias = cb[t];
        float* pe = pemb + (size_t)(4 * b) * DD + t;
        pe[0]      = a0 + bias;
        pe[DD]     = a1 + bias;
        pe[2 * DD] = a2 + bias;
        pe[3 * DD] = a3 + bias;
    }

    /* ---- per-b column mean + L2-norm factor (block-local) ---- */
    comb[g * 192 + c] = s;
    __syncthreads();
    if (g == 0) {
        f32x4 s0 = comb[c], s1 = comb[192 + c], s2 = comb[384 + c], s3 = comb[576 + c];
        f32x4 m4 = (s0 + s1 + s2 + s3) * (1.0f / NN);
        xm[4 * c + 0] = m4.x;
        xm[4 * c + 1] = m4.y;
        xm[4 * c + 2] = m4.z;
        xm[4 * c + 3] = m4.w;
    }
    __syncthreads();
    float sq = xm[t] * xm[t];
#pragma unroll
    for (int off = 32; off; off >>= 1) sq += __shfl_down(sq, off);
    if ((t & 63) == 0) wred[t >> 6] = sq;
    __syncthreads();
    if (t == 0) {
        float tot = 0.f;
        for (int i = 0; i < 12; ++i) tot += wred[i];
        rsh = rsqrtf(fmaxf(tot, 1e-12f));
    }
    __syncthreads();
    const float r = rsh;

    /* ---- sync #1: pnorm/pemb now visible everywhere ---- */
    __threadfence();
    cg::this_grid().sync();

    /* ---- 32 sim dots (16 threads per prompt) ---- */
    if (t < 512) {
        const int p = t >> 4, sub = t & 15;
        const float* pr = pnorm + (size_t)p * DD;
        float acc = 0.f;
#pragma unroll 8
        for (int j = 0; j < 48; ++j) {
            const int k = sub + (j << 4);
            acc += xm[k] * pr[k];
        }
        acc += __shfl_down(acc, 8, 16);
        acc += __shfl_down(acc, 4, 16);
        acc += __shfl_down(acc, 2, 16);
        acc += __shfl_down(acc, 1, 16);
        if (sub == 0) {
            const float sv = acc * r;
            sims[p] = sv;
            out[SIM_OFF + b * PP + p] = sv;
        }
    }
    __syncthreads();

    /* ---- wave-parallel top-5 on wave 0 (tie-break: lowest index) ---- */
    if (t < 64) {
        float v = (t < PP) ? sims[t] : -1e30f;
        float rsum = 0.f;
#pragma unroll
        for (int k = 0; k < TOPK; ++k) {
            float bv = v; int bbi = t;
#pragma unroll
            for (int off = 32; off; off >>= 1) {
                const float ov = __shfl_xor(bv, off);
                const int   oi = __shfl_xor(bbi, off);
                if (ov > bv || (ov == bv && oi < bbi)) { bv = ov; bbi = oi; }
            }
            if (t == 0) {
                lidx[k] = bbi;
                out[IDX_OFF + b * TOPK + k] = (float)bbi;
                rsum += bv;
            }
            if (t == bbi) v = -1e30f;
        }
        if (t == 0) wspart[b] = rsum;
    }
    __syncthreads();

    /* ---- gather 20 prompt-embed rows (L2-resident) into out0[0..20) ---- */
    f32x4* dst = (f32x4*)(out + (size_t)b * (NROW * DD));
    const f32x4* src = (const f32x4*)pemb;            /* 192 f32x4 per row */
    for (int v = t; v < 20 * 192; v += 768) {
        const int row = v / 192;
        const int off = v - row * 192;
        const int srow = lidx[row >> 2] * 4 + (row & 3);
        __builtin_nontemporal_store(src[srow * 192 + off], dst + row * 192 + off);
    }

    /* ---- sync #2: partials ready -> block 0 reduces reduce_sim ---- */
    __threadfence();
    cg::this_grid().sync();
    if (b == 0) {
        float sv = (t < BB) ? wspart[t] : 0.f;
#pragma unroll
        for (int off = 32; off; off >>= 1) sv += __shfl_down(sv, off);
        if ((t & 63) == 0) wred[t >> 6] = sv;
        __syncthreads();
        if (t == 0) {
            float tot = 0.f;
            for (int i = 0; i < 12; ++i) tot += wred[i];
            out[RS_OFF] = tot * (1.0f / BB);
        }
    }
}

extern "C" void kernel_launch(void* const* d_in, const int* in_sizes, int n_in,
                              void* d_out, int out_size, void* d_ws, size_t ws_size,
                              hipStream_t stream) {
    const float* x      = (const float*)d_in[0];   /* x_embed   (256,196,768) fp32 */
    const float* prompt = (const float*)d_in[1];   /* prompt    (32,3,32,32)  fp32 */
    const float* pkey   = (const float*)d_in[2];   /* prompt_key(32,768)      fp32 */
    const float* cw     = (const float*)d_in[3];   /* conv_w    (768,3,16,16) fp32 */
    const float* cb     = (const float*)d_in[4];   /* conv_b    (768,)        fp32 */
    float* out = (float*)d_out;
    char* ws = (char*)d_ws;

    float* pnorm  = (float*)(ws + WS_PNORM);
    float* pemb   = (float*)(ws + WS_PEMB);
    float* wspart = (float*)(ws + WS_PART);

    void* args[] = {(void*)&x, (void*)&prompt, (void*)&pkey, (void*)&cw, (void*)&cb,
                    (void*)&out, (void*)&pnorm, (void*)&pemb, (void*)&wspart};
    hipLaunchCooperativeKernel((void*)k_all, dim3(BB), dim3(768), args, 0, stream);
}

// Round 4
// 331.261 us; speedup vs baseline: 1.8593x; 1.8593x over previous
//
#include <hip/hip_runtime.h>

typedef float __attribute__((ext_vector_type(4))) f32x4;

#define BB 256
#define NN 196
#define DD 768
#define PP 32
#define TOPK 5
#define NROW 216           /* 20 + 196 */

/* fp32 element offsets in d_out (flat concat in return order) */
#define OUT0_ELTS (BB * NROW * DD)   /* 42467328 */
#define RS_OFF    OUT0_ELTS
#define SIM_OFF   (OUT0_ELTS + 1)
#define IDX_OFF   (OUT0_ELTS + 1 + BB * PP)

/* ws layout (byte offsets) */
#define WS_PEMB   0                          /* 128*768 fp32 = 393216 B */

/* ---- Kernel 1: patch embed only (96 blocks x 256 threads).
   4 positions x 256 channels per block; patches staged in LDS so each
   conv_w float4 is reused 4x in registers. */
__global__ __launch_bounds__(256) void k_prep(const float* __restrict__ prompt,
                                              const float* __restrict__ cw,
                                              const float* __restrict__ cb,
                                              float* __restrict__ pemb) {
    const int t = threadIdx.x;
    const int bxx = blockIdx.x;                 /* 0..95 */
    const int chunk = bxx / 32, pg = bxx - chunk * 32;
    const int m0 = pg * 4;                      /* 4 positions m0..m0+3 */
    const int n = chunk * 256 + t;              /* output channel */
    __shared__ float patch[4 * DD];
    for (int idx = t; idx < 4 * DD; idx += 256) {
        const int j = idx / DD, kk = idx - j * DD;
        const int c = kk >> 8, rem = kk & 255;
        const int kh = rem >> 4, kw = rem & 15;
        const int m = m0 + j;
        const int p = m >> 2, l = m & 3;
        patch[idx] = prompt[(size_t)p * 3072 + (size_t)c * 1024
                            + ((l >> 1) * 16 + kh) * 32 + (l & 1) * 16 + kw];
    }
    __syncthreads();
    const float4* wrow = (const float4*)(cw + (size_t)n * DD);
    const float4* p0 = (const float4*)(patch);
    const float4* p1 = (const float4*)(patch + DD);
    const float4* p2 = (const float4*)(patch + 2 * DD);
    const float4* p3 = (const float4*)(patch + 3 * DD);
    float a0 = 0.f, a1 = 0.f, a2 = 0.f, a3 = 0.f;
#pragma unroll 4
    for (int kk = 0; kk < 192; ++kk) {
        const float4 w = wrow[kk];
        const float4 q0 = p0[kk], q1 = p1[kk], q2 = p2[kk], q3 = p3[kk];
        a0 += q0.x * w.x + q0.y * w.y + q0.z * w.z + q0.w * w.w;
        a1 += q1.x * w.x + q1.y * w.y + q1.z * w.z + q1.w * w.w;
        a2 += q2.x * w.x + q2.y * w.y + q2.z * w.z + q2.w * w.w;
        a3 += q3.x * w.x + q3.y * w.y + q3.z * w.z + q3.w * w.w;
    }
    const float bias = cb[n];
    pemb[(size_t)(m0 + 0) * DD + n] = a0 + bias;
    pemb[(size_t)(m0 + 1) * DD + n] = a1 + bias;
    pemb[(size_t)(m0 + 2) * DD + n] = a2 + bias;
    pemb[(size_t)(m0 + 3) * DD + n] = a3 + bias;
}

/* ---- Kernel 2 (fused, heavy): per batch b — software-pipelined NT copy
   of 196 x-rows into out0[20..216) with fused column-sum, mean, L2-norm,
   32 sim dots (with in-loop pkey normalization — no pnorm buffer),
   wave-parallel top-5, sim/idx writes, atomic reduce_sim contribution,
   then gather 20 prompt-embed rows into out0[0..20). */
__global__ __launch_bounds__(768) void k_fused(const float* __restrict__ x,
                                               const float* __restrict__ pkey,
                                               const float* __restrict__ pemb,
                                               float* __restrict__ out) {
    const int b = blockIdx.x;
    const int t = threadIdx.x;
    const int g = t / 192, c = t - g * 192;       /* c: float4-column 0..191 */
    const float* xb = x + (size_t)b * (NN * DD);
    float* ob = out + (size_t)b * (NROW * DD) + 20 * DD;
    f32x4 s = (f32x4)(0.f);
    /* 49 rows per thread group in 7 groups of 7.  Pipeline: prefetch the
       next group's 7 NT loads BEFORE storing the current group, so loads
       (issued first) can be waited on without draining the NT stores. */
    f32x4 va[7], vb[7];
#pragma unroll
    for (int i = 0; i < 7; ++i)
        va[i] = __builtin_nontemporal_load((const f32x4*)(xb + (size_t)(g + 4 * i) * DD) + c);
#pragma unroll
    for (int o = 0; o < 7; ++o) {
        if (o < 6) {
#pragma unroll
            for (int i = 0; i < 7; ++i) {
                const int row = g + 4 * ((o + 1) * 7 + i);
                vb[i] = __builtin_nontemporal_load((const f32x4*)(xb + (size_t)row * DD) + c);
            }
        }
#pragma unroll
        for (int i = 0; i < 7; ++i) {
            const int row = g + 4 * (o * 7 + i);
            s += va[i];
            __builtin_nontemporal_store(va[i], (f32x4*)(ob + (size_t)row * DD) + c);
        }
#pragma unroll
        for (int i = 0; i < 7; ++i) va[i] = vb[i];
    }
    __shared__ f32x4 comb[768];
    __shared__ float xm[768];
    __shared__ float sims[PP];
    __shared__ float wred[12];
    __shared__ float rsh;
    __shared__ int lidx[TOPK];
    comb[g * 192 + c] = s;
    __syncthreads();
    if (g == 0) {
        f32x4 s0 = comb[c], s1 = comb[192 + c], s2 = comb[384 + c], s3 = comb[576 + c];
        f32x4 m4 = (s0 + s1 + s2 + s3) * (1.0f / NN);
        xm[4 * c + 0] = m4.x;
        xm[4 * c + 1] = m4.y;
        xm[4 * c + 2] = m4.z;
        xm[4 * c + 3] = m4.w;
    }
    __syncthreads();
    float sq = xm[t] * xm[t];
#pragma unroll
    for (int off = 32; off; off >>= 1) sq += __shfl_down(sq, off);
    if ((t & 63) == 0) wred[t >> 6] = sq;
    __syncthreads();
    if (t == 0) {
        float tot = 0.f;
        for (int i = 0; i < 12; ++i) tot += wred[i];
        rsh = rsqrtf(fmaxf(tot, 1e-12f));
    }
    __syncthreads();
    const float r = rsh;
    /* ---- 32 sim dots, 16 threads per prompt; pkey row normalized
       in-loop (second accumulator on the same loads) ---- */
    if (t < 512) {
        const int p = t >> 4, sub = t & 15;
        const float* pr = pkey + (size_t)p * DD;
        float acc = 0.f, nrm = 0.f;
#pragma unroll 8
        for (int j = 0; j < 48; ++j) {
            const int k = sub + (j << 4);
            const float pk = pr[k];
            acc += xm[k] * pk;
            nrm += pk * pk;
        }
        acc += __shfl_down(acc, 8, 16);  nrm += __shfl_down(nrm, 8, 16);
        acc += __shfl_down(acc, 4, 16);  nrm += __shfl_down(nrm, 4, 16);
        acc += __shfl_down(acc, 2, 16);  nrm += __shfl_down(nrm, 2, 16);
        acc += __shfl_down(acc, 1, 16);  nrm += __shfl_down(nrm, 1, 16);
        if (sub == 0) {
            const float sv = acc * rsqrtf(fmaxf(nrm, 1e-12f)) * r;
            sims[p] = sv;
            out[SIM_OFF + b * PP + p] = sv;
        }
    }
    __syncthreads();
    /* ---- wave-parallel top-5 on wave 0 (tie-break: lowest index) ---- */
    if (t < 64) {
        float v = (t < PP) ? sims[t] : -1e30f;
        float rsum = 0.f;
#pragma unroll
        for (int k = 0; k < TOPK; ++k) {
            float bv = v; int bbi = t;
#pragma unroll
            for (int off = 32; off; off >>= 1) {
                const float ov = __shfl_xor(bv, off);
                const int   oi = __shfl_xor(bbi, off);
                if (ov > bv || (ov == bv && oi < bbi)) { bv = ov; bbi = oi; }
            }
            if (t == 0) {
                lidx[k] = bbi;
                out[IDX_OFF + b * TOPK + k] = (float)bbi;
                rsum += bv;
            }
            if (t == bbi) v = -1e30f;
        }
        if (t == 0) atomicAdd(&out[RS_OFF], rsum * (1.0f / BB));
    }
    __syncthreads();
    /* ---- gather 20 prompt-embed rows (L2-resident) into out0[0..20) ---- */
    f32x4* dst = (f32x4*)(out + (size_t)b * (NROW * DD));
    const f32x4* src = (const f32x4*)pemb;            /* 192 f32x4 per row */
    for (int v = t; v < 20 * 192; v += 768) {
        const int row = v / 192;
        const int off = v - row * 192;
        const int srow = lidx[row >> 2] * 4 + (row & 3);
        __builtin_nontemporal_store(src[srow * 192 + off], dst + row * 192 + off);
    }
}

extern "C" void kernel_launch(void* const* d_in, const int* in_sizes, int n_in,
                              void* d_out, int out_size, void* d_ws, size_t ws_size,
                              hipStream_t stream) {
    const float* x      = (const float*)d_in[0];   /* x_embed   (256,196,768) fp32 */
    const float* prompt = (const float*)d_in[1];   /* prompt    (32,3,32,32)  fp32 */
    const float* pkey   = (const float*)d_in[2];   /* prompt_key(32,768)      fp32 */
    const float* cw     = (const float*)d_in[3];   /* conv_w    (768,3,16,16) fp32 */
    const float* cb     = (const float*)d_in[4];   /* conv_b    (768,)        fp32 */
    float* out = (float*)d_out;
    char* ws = (char*)d_ws;

    float* pemb = (float*)(ws + WS_PEMB);

    /* zero the reduce_sim accumulator (stream-ordered, graph-capturable) */
    hipMemsetAsync(out + RS_OFF, 0, sizeof(float), stream);
    k_prep<<<96, 256, 0, stream>>>(prompt, cw, cb, pemb);
    k_fused<<<BB, 768, 0, stream>>>(x, pkey, pemb, out);
}